// Round 14
// baseline (434.357 us; speedup 1.0000x reference)
//
#include <hip/hip_runtime.h>
#include <hip/hip_bf16.h>

// GCN 3-layer: GCNConv -> BN -> ReLU (x2) -> GCNConv -> +residual
// N=50000, E=800000, D=128, fp32 in/out.
//
// Round 14 (= round 12 source, resubmitted through infra failures): bucketed
// 2-phase CSR fill (kills the 56MB scatter-writeback: random 4B writes x 64B
// lines x 8 XCDs).
//   - fillA: edges -> 16 dst-range buckets x 8 XCD-replicas (replica=blockIdx&7
//     = XCD, append-frontier L2-local); embeds the degree histogram.
//   - fillB: bucket = blockIdx&15 -> XCD b%8; esrc window (~262KB) + cur window
//     (16KB) L2-resident -> scatter is L2-local, writeback once.
//   - prep_all fuses x->bf16 cast, 3x W^T bf16, cnt/bcur zeroing; prep_bn
//     fuses both BN folds. 18 -> 13 launches.
//   - mm_mfma / agg_kernel identical to round-11 (passed, absmax 0.031).

#define GCN_N 50000
#define GCN_E 800000
#define GCN_D 128
#define NBK 16      // dst buckets (d>>12); 13 used for N=50000
#define NREP 8      // XCD replicas per bucket
#define SEGCAP 16384  // pairs per (bucket,replica); expected ~8.2K, >>40 sigma

using bf16x8 = __attribute__((ext_vector_type(8))) short;
using f32x4  = __attribute__((ext_vector_type(4))) float;

// bf16 helpers (bit ops; finite values only)
__device__ __forceinline__ float bflo(unsigned u) { return __uint_as_float(u << 16); }
__device__ __forceinline__ float bfhi(unsigned u) { return __uint_as_float(u & 0xffff0000u); }
__device__ __forceinline__ unsigned f2bf(float f) {          // round-to-nearest-even
    unsigned u = __float_as_uint(f);
    return (u + 0x7fffu + ((u >> 16) & 1u)) >> 16;
}

// ------------------------------------------------- fused one-time prep
// grid 3125 x 256 = 800000 threads: castx (8 elems/thread), zero cnt/bcur,
// build Wt = W^T in bf16 for all three layers.
__global__ __launch_bounds__(256) void prep_all(const float* __restrict__ x,
                                                unsigned short* __restrict__ xb,
                                                const float* __restrict__ W1,
                                                const float* __restrict__ W2,
                                                const float* __restrict__ W3,
                                                unsigned short* __restrict__ wt1,
                                                unsigned short* __restrict__ wt2,
                                                unsigned short* __restrict__ wt3,
                                                int* __restrict__ cnt,
                                                int* __restrict__ bcur) {
    int gid = blockIdx.x * 256 + threadIdx.x;
    int i = gid * 8;
    if (i + 7 < GCN_N * GCN_D) {
        float4 f0 = *(const float4*)&x[i];
        float4 f1 = *(const float4*)&x[i + 4];
        uint4 o;
        o.x = f2bf(f0.x) | (f2bf(f0.y) << 16);
        o.y = f2bf(f0.z) | (f2bf(f0.w) << 16);
        o.z = f2bf(f1.x) | (f2bf(f1.y) << 16);
        o.w = f2bf(f1.z) | (f2bf(f1.w) << 16);
        *(uint4*)&xb[i] = o;
    }
    if (gid < GCN_N) cnt[gid] = 0;
    if (gid < NBK * NREP) bcur[gid] = 0;
    if (gid < GCN_D * GCN_D) {
        int nn = gid >> 7, k = gid & 127;
        wt1[gid] = (unsigned short)f2bf(W1[k * 128 + nn]);
        wt2[gid] = (unsigned short)f2bf(W2[k * 128 + nn]);
        wt3[gid] = (unsigned short)f2bf(W3[k * 128 + nn]);
    }
}

// ------------------------------------------------- fill phase A (+histogram)
// Edge -> (src,dst) pair appended to segment (bucket = dst>>12, rep = blockIdx&7).
// rep == XCD (round-robin dispatch) -> append frontier is single-XCD L2-local.
__global__ __launch_bounds__(256) void fillA(const int* __restrict__ src,
                                             const int* __restrict__ dst,
                                             int* __restrict__ cnt,
                                             int* __restrict__ bcur,
                                             int2* __restrict__ pairs, int nE) {
    __shared__ int lcnt[NBK];
    __shared__ int lbase[NBK];
    int tid = threadIdx.x;
    if (tid < NBK) lcnt[tid] = 0;
    __syncthreads();
    int e = blockIdx.x * 256 + tid;
    int rep = blockIdx.x & (NREP - 1);
    int s = 0, d = 0, b = 0, off = 0;
    bool valid = e < nE;
    if (valid) {
        s = src[e];
        d = dst[e];
        atomicAdd(&cnt[d], 1);          // degree histogram (was hist_kernel)
        b = d >> 12;
        off = atomicAdd(&lcnt[b], 1);   // LDS atomic: fast
    }
    __syncthreads();
    if (tid < NBK)
        lbase[tid] = lcnt[tid] ? atomicAdd(&bcur[tid * NREP + rep], lcnt[tid]) : 0;
    __syncthreads();
    if (valid)
        pairs[(size_t)(b * NREP + rep) * SEGCAP + lbase[b] + off] = make_int2(s, d);
}

// ------------------------------------------------- fill phase B (L2-local scatter)
// grid = 32 x 16; bucket = blockIdx&15 -> XCD bucket%8 (16 % 8 == 0).
// Bucket's esrc window (~262KB) + cur window (16KB) stay L2-resident.
__global__ __launch_bounds__(256) void fillB(const int2* __restrict__ pairs,
                                             const int* __restrict__ bcur,
                                             const int* __restrict__ row_ptr,
                                             int* __restrict__ cur,
                                             int* __restrict__ esrc) {
    int b = blockIdx.x & (NBK - 1);
    int j = blockIdx.x >> 4;            // 0..31
    int tid = threadIdx.x;
    #pragma unroll
    for (int r = 0; r < NREP; ++r) {
        int cr = bcur[b * NREP + r];
        const int2* seg = pairs + (size_t)(b * NREP + r) * SEGCAP;
        for (int i = j * 256 + tid; i < cr; i += 32 * 256) {
            int2 p = seg[i];
            int pos = row_ptr[p.y] + atomicAdd(&cur[p.y], 1);
            esrc[pos] = p.x;
        }
    }
}

// ------------------------------------------------- multi-block prefix sum
__global__ __launch_bounds__(256) void block_reduce(const int* __restrict__ cnt,
                                                    int* __restrict__ bsum, int n) {
    int tid = threadIdx.x, lane = tid & 63, wid = tid >> 6;
    int i0 = blockIdx.x * 1024 + tid * 4;
    int s = 0;
    #pragma unroll
    for (int q = 0; q < 4; ++q)
        if (i0 + q < n) s += cnt[i0 + q];
    #pragma unroll
    for (int off = 32; off >= 1; off >>= 1) s += __shfl_xor(s, off);
    __shared__ int ws[4];
    if (lane == 0) ws[wid] = s;
    __syncthreads();
    if (tid == 0) bsum[blockIdx.x] = ws[0] + ws[1] + ws[2] + ws[3];
}

__global__ void scan_bsums(const int* __restrict__ bsum, int* __restrict__ boff,
                           int nb, int* __restrict__ row_last) {
    int lane = threadIdx.x;  // 64 threads
    int v = (lane < nb) ? bsum[lane] : 0;
    int sc = v;
    #pragma unroll
    for (int off = 1; off < 64; off <<= 1) {
        int t = __shfl_up(sc, off);
        if (lane >= off) sc += t;
    }
    if (lane < nb) boff[lane] = sc - v;
    if (lane == 63) *row_last = sc;  // row_ptr[N] = E
}

// row_ptr (exclusive scan), dinv = rsqrt(deg+1), zero cnt for fill cursor.
__global__ __launch_bounds__(256) void scan_apply(const int* __restrict__ cnt_in,
                                                  const int* __restrict__ boff,
                                                  int* __restrict__ row_ptr,
                                                  float* __restrict__ dinv,
                                                  int* __restrict__ cnt_zero, int n) {
    __shared__ int wsum[4];
    int tid = threadIdx.x, lane = tid & 63, wid = tid >> 6;
    int i0 = blockIdx.x * 1024 + tid * 4;
    int a0 = 0, a1 = 0, a2 = 0, a3 = 0;
    if (i0 + 0 < n) a0 = cnt_in[i0 + 0];
    if (i0 + 1 < n) a1 = cnt_in[i0 + 1];
    if (i0 + 2 < n) a2 = cnt_in[i0 + 2];
    if (i0 + 3 < n) a3 = cnt_in[i0 + 3];
    int tsum = a0 + a1 + a2 + a3;
    int sc = tsum;
    #pragma unroll
    for (int off = 1; off < 64; off <<= 1) {
        int t = __shfl_up(sc, off);
        if (lane >= off) sc += t;
    }
    if (lane == 63) wsum[wid] = sc;
    __syncthreads();
    int woff = 0;
    #pragma unroll
    for (int w = 0; w < 4; ++w)
        if (w < wid) woff += wsum[w];
    int excl = boff[blockIdx.x] + woff + (sc - tsum);
    if (i0 + 0 < n) { row_ptr[i0 + 0] = excl;                dinv[i0 + 0] = rsqrtf((float)a0 + 1.f); cnt_zero[i0 + 0] = 0; }
    if (i0 + 1 < n) { row_ptr[i0 + 1] = excl + a0;           dinv[i0 + 1] = rsqrtf((float)a1 + 1.f); cnt_zero[i0 + 1] = 0; }
    if (i0 + 2 < n) { row_ptr[i0 + 2] = excl + a0 + a1;      dinv[i0 + 2] = rsqrtf((float)a2 + 1.f); cnt_zero[i0 + 2] = 0; }
    if (i0 + 3 < n) { row_ptr[i0 + 3] = excl + a0 + a1 + a2; dinv[i0 + 3] = rsqrtf((float)a3 + 1.f); cnt_zero[i0 + 3] = 0; }
}

// ------------------------------------------------- fused BN folds (2 layers)
__global__ void prep_bn(const float* __restrict__ b1, const float* __restrict__ g1,
                        const float* __restrict__ be1, const float* __restrict__ m1,
                        const float* __restrict__ v1, float* __restrict__ scale1,
                        float* __restrict__ shift1,
                        const float* __restrict__ b2, const float* __restrict__ g2,
                        const float* __restrict__ be2, const float* __restrict__ m2,
                        const float* __restrict__ v2, float* __restrict__ scale2,
                        float* __restrict__ shift2) {
    int c = threadIdx.x;
    if (blockIdx.x == 0) {
        float s = g1[c] * rsqrtf(v1[c] + 1e-5f);
        scale1[c] = s;
        shift1[c] = (b1[c] - m1[c]) * s + be1[c];
    } else {
        float s = g2[c] * rsqrtf(v2[c] + 1e-5f);
        scale2[c] = s;
        shift2[c] = (b2[c] - m2[c]) * s + be2[c];
    }
}

// ---------------------------------------------------------------- MFMA matmul
// hb[node][128] (bf16) = dinv[node] * (A[node,:] @ W);  A bf16, Wt = W^T bf16.
// (identical to round-11 verified version)
__global__ __launch_bounds__(256) void mm_mfma(const unsigned short* __restrict__ A,
                                               const unsigned short* __restrict__ Wt,
                                               const float* __restrict__ dinv,
                                               unsigned short* __restrict__ hb, int n) {
    __shared__ unsigned short Cs[64][136];   // pad to 272B stride
    int tid = threadIdx.x;
    int w = tid >> 6, l = tid & 63;
    int lg = l >> 4, li = l & 15;
    int row0 = blockIdx.x * 64;

    int arow = row0 + w * 16 + li;
    int arow_c = min(arow, n - 1);
    const unsigned short* ap = A + (size_t)arow_c * GCN_D + lg * 8;
    bf16x8 a[4];
    #pragma unroll
    for (int k0 = 0; k0 < 4; ++k0) a[k0] = *(const bf16x8*)(ap + k0 * 32);

    f32x4 acc[8];
    #pragma unroll
    for (int t = 0; t < 8; ++t) acc[t] = (f32x4){0.f, 0.f, 0.f, 0.f};

    #pragma unroll
    for (int t = 0; t < 8; ++t) {
        const unsigned short* bp = Wt + (size_t)(t * 16 + li) * GCN_D + lg * 8;
        #pragma unroll
        for (int k0 = 0; k0 < 4; ++k0) {
            bf16x8 b = *(const bf16x8*)(bp + k0 * 32);
            acc[t] = __builtin_amdgcn_mfma_f32_16x16x32_bf16(a[k0], b, acc[t], 0, 0, 0);
        }
    }

    // epilogue: scale by dinv, pack bf16, stage in LDS
    int crow = w * 16 + lg * 4;
    float dv[4];
    #pragma unroll
    for (int r = 0; r < 4; ++r) dv[r] = dinv[min(row0 + crow + r, n - 1)];
    #pragma unroll
    for (int t = 0; t < 8; ++t)
        #pragma unroll
        for (int r = 0; r < 4; ++r)
            Cs[crow + r][t * 16 + li] = (unsigned short)f2bf(acc[t][r] * dv[r]);
    __syncthreads();

    // coalesced store: thread -> row tid>>2, 32-col chunk tid&3
    int orow = tid >> 2;
    int gr = row0 + orow;
    if (gr < n) {
        const unsigned short* sp = &Cs[orow][(tid & 3) * 32];
        uint4* dp = (uint4*)&hb[(size_t)gr * GCN_D + (tid & 3) * 32];
        dp[0] = *(const uint4*)(sp + 0);
        dp[1] = *(const uint4*)(sp + 8);
        dp[2] = *(const uint4*)(sp + 16);
        dp[3] = *(const uint4*)(sp + 24);
    }
}

// ------------------------------------------------- fused aggregate + epilogue
// (identical to round-11 verified version)
template <int FINAL>
__global__ __launch_bounds__(256) void agg_kernel(const unsigned short* __restrict__ hb,
                                                  const int* __restrict__ row_ptr,
                                                  const int* __restrict__ esrc,
                                                  const float* __restrict__ dinv,
                                                  const float* __restrict__ scale,
                                                  const float* __restrict__ shift,
                                                  const float* __restrict__ xres,
                                                  unsigned short* __restrict__ outb,
                                                  float* __restrict__ outf, int n) {
    int wid = threadIdx.x >> 6, lane = threadIdx.x & 63;
    int node = blockIdx.x * 4 + wid;
    if (node >= n) return;
    int cc = lane * 2;  // channel pair
    unsigned us = *(const unsigned*)&hb[(size_t)node * GCN_D + cc];
    float aLo = bflo(us), aHi = bfhi(us);   // self term h'[dst]
    float bLo = 0.f, bHi = 0.f;
    int j = row_ptr[node], end = row_ptr[node + 1];
    for (; j + 8 <= end; j += 8) {
        int s0 = esrc[j + 0], s1 = esrc[j + 1], s2 = esrc[j + 2], s3 = esrc[j + 3];
        int s4 = esrc[j + 4], s5 = esrc[j + 5], s6 = esrc[j + 6], s7 = esrc[j + 7];
        unsigned u0 = *(const unsigned*)&hb[(size_t)s0 * GCN_D + cc];
        unsigned u1 = *(const unsigned*)&hb[(size_t)s1 * GCN_D + cc];
        unsigned u2 = *(const unsigned*)&hb[(size_t)s2 * GCN_D + cc];
        unsigned u3 = *(const unsigned*)&hb[(size_t)s3 * GCN_D + cc];
        unsigned u4 = *(const unsigned*)&hb[(size_t)s4 * GCN_D + cc];
        unsigned u5 = *(const unsigned*)&hb[(size_t)s5 * GCN_D + cc];
        unsigned u6 = *(const unsigned*)&hb[(size_t)s6 * GCN_D + cc];
        unsigned u7 = *(const unsigned*)&hb[(size_t)s7 * GCN_D + cc];
        aLo += bflo(u0) + bflo(u1);  aHi += bfhi(u0) + bfhi(u1);
        bLo += bflo(u2) + bflo(u3);  bHi += bfhi(u2) + bfhi(u3);
        aLo += bflo(u4) + bflo(u5);  aHi += bfhi(u4) + bfhi(u5);
        bLo += bflo(u6) + bflo(u7);  bHi += bfhi(u6) + bfhi(u7);
    }
    for (; j < end; ++j) {
        int s = esrc[j];
        unsigned u = *(const unsigned*)&hb[(size_t)s * GCN_D + cc];
        aLo += bflo(u);  aHi += bfhi(u);
    }
    float dvn = dinv[node];
    float vx = (aLo + bLo) * dvn;
    float vy = (aHi + bHi) * dvn;
    if (FINAL) {
        float2 b = *(const float2*)&scale[cc];   // b3 passed via 'scale'
        float2 xr = *(const float2*)&xres[(size_t)node * GCN_D + cc];
        float2 o;
        o.x = vx + b.x + xr.x;
        o.y = vy + b.y + xr.y;
        *(float2*)&outf[(size_t)node * GCN_D + cc] = o;
    } else {
        float2 sc = *(const float2*)&scale[cc];
        float2 sh = *(const float2*)&shift[cc];
        float ox = fmaxf(vx * sc.x + sh.x, 0.f);
        float oy = fmaxf(vy * sc.y + sh.y, 0.f);
        *(unsigned*)&outb[(size_t)node * GCN_D + cc] = f2bf(ox) | (f2bf(oy) << 16);
    }
}

// ---------------------------------------------------------------- launch
extern "C" void kernel_launch(void* const* d_in, const int* in_sizes, int n_in,
                              void* d_out, int out_size, void* d_ws, size_t ws_size,
                              hipStream_t stream) {
    (void)in_sizes; (void)n_in; (void)out_size; (void)ws_size;
    const int N = GCN_N, E = GCN_E, D = GCN_D;

    const float* x   = (const float*)d_in[0];
    const float* W1  = (const float*)d_in[1];
    const float* b1  = (const float*)d_in[2];
    const float* g1  = (const float*)d_in[3];
    const float* be1 = (const float*)d_in[4];
    const float* m1  = (const float*)d_in[5];
    const float* v1  = (const float*)d_in[6];
    const float* W2  = (const float*)d_in[7];
    const float* b2  = (const float*)d_in[8];
    const float* g2  = (const float*)d_in[9];
    const float* be2 = (const float*)d_in[10];
    const float* m2  = (const float*)d_in[11];
    const float* v2  = (const float*)d_in[12];
    const float* W3  = (const float*)d_in[13];
    const float* b3  = (const float*)d_in[14];
    const int* src   = (const int*)d_in[15];
    const int* dst   = (const int*)d_in[16];
    float* out = (float*)d_out;

    // workspace layout (bf16 buffers first, then 4/8B-typed)
    unsigned short* hb   = (unsigned short*)d_ws;        // N*D bf16
    unsigned short* actb = hb + (size_t)N * D;           // N*D bf16
    unsigned short* xb   = actb + (size_t)N * D;         // N*D bf16
    unsigned short* wt1  = xb + (size_t)N * D;           // 16384
    unsigned short* wt2  = wt1 + D * D;
    unsigned short* wt3  = wt2 + D * D;
    float* dinv   = (float*)(wt3 + D * D);               // N (even short count)
    int* cnt      = (int*)(dinv + N);                    // N
    int* row_ptr  = cnt + N;                             // N+1
    int* esrc     = row_ptr + (N + 2);                   // E
    float* scale1 = (float*)(esrc + E);                  // 128
    float* shift1 = scale1 + D;
    float* scale2 = shift1 + D;
    float* shift2 = scale2 + D;
    int* bsum     = (int*)(shift2 + D);                  // 64
    int* boff     = bsum + 64;                           // 64
    int* bcur     = boff + 64;                           // NBK*NREP = 128
    int2* pairs   = (int2*)(bcur + NBK * NREP);          // NBK*NREP*SEGCAP (16.8MB)

    const int NB = (N + 1023) / 1024;  // 49 scan blocks

    // ---- one-time prep + CSR build
    prep_all<<<(N * D) / (256 * 8), 256, 0, stream>>>(x, xb, W1, W2, W3,
                                                      wt1, wt2, wt3, cnt, bcur);
    fillA<<<(E + 255) / 256, 256, 0, stream>>>(src, dst, cnt, bcur, pairs, E);
    block_reduce<<<NB, 256, 0, stream>>>(cnt, bsum, N);
    scan_bsums<<<1, 64, 0, stream>>>(bsum, boff, NB, &row_ptr[N]);
    scan_apply<<<NB, 256, 0, stream>>>(cnt, boff, row_ptr, dinv, cnt, N);
    fillB<<<32 * NBK, 256, 0, stream>>>(pairs, bcur, row_ptr, cnt, esrc);
    prep_bn<<<2, D, 0, stream>>>(b1, g1, be1, m1, v1, scale1, shift1,
                                 b2, g2, be2, m2, v2, scale2, shift2);

    int mm_grid = (N + 63) / 64;
    int agg_grid = (N + 3) / 4;

    // ---- layer 1
    mm_mfma<<<mm_grid, 256, 0, stream>>>(xb, wt1, dinv, hb, N);
    agg_kernel<0><<<agg_grid, 256, 0, stream>>>(hb, row_ptr, esrc, dinv,
                                                scale1, shift1, nullptr, actb, nullptr, N);
    // ---- layer 2
    mm_mfma<<<mm_grid, 256, 0, stream>>>(actb, wt2, dinv, hb, N);
    agg_kernel<0><<<agg_grid, 256, 0, stream>>>(hb, row_ptr, esrc, dinv,
                                                scale2, shift2, nullptr, actb, nullptr, N);
    // ---- layer 3 (+bias +residual, writes fp32 d_out)
    mm_mfma<<<mm_grid, 256, 0, stream>>>(actb, wt3, dinv, hb, N);
    agg_kernel<1><<<agg_grid, 256, 0, stream>>>(hb, row_ptr, esrc, dinv,
                                                b3, nullptr, x, nullptr, out, N);
}

// Round 15
// 388.107 us; speedup vs baseline: 1.1192x; 1.1192x over previous
//
#include <hip/hip_runtime.h>
#include <hip/hip_bf16.h>

// GCN 3-layer: GCNConv -> BN -> ReLU (x2) -> GCNConv -> +residual
// N=50000, E=800000, D=128, fp32 in/out.
//
// Round 15: CSR build v2 (r14's fillA regressed 91us: fused histogram's random
// cross-XCD atomics drained at __syncthreads + 50K hot reservation atomics).
//   - fillA: PURE partition, 2048 edges/block, LDS-staged, dense segment
//     writes (~6.5MB), 6K reservation atomics on 16 counters.
//   - histB: degree histogram AFTER partitioning; bucket=blockIdx&15 -> XCD
//     b%8; cnt window 16KB L2-local -> no cross-XCD atomic bouncing.
//   - fillB: scatter within L2-resident bucket windows (esrc ~250KB, cur 16KB).
//   - mm_mfma / agg_kernel / prep_all / prep_bn / scan chain: r11-proven.

#define GCN_N 50000
#define GCN_E 800000
#define GCN_D 128
#define NBK 16          // dst buckets (d>>12); 13 used for N=50000
#define SEGCAP 73728    // pairs per bucket; expected 65.5K, +18 sigma margin
#define FA_BATCH 2048   // edges per fillA block

using bf16x8 = __attribute__((ext_vector_type(8))) short;
using f32x4  = __attribute__((ext_vector_type(4))) float;

// bf16 helpers (bit ops; finite values only)
__device__ __forceinline__ float bflo(unsigned u) { return __uint_as_float(u << 16); }
__device__ __forceinline__ float bfhi(unsigned u) { return __uint_as_float(u & 0xffff0000u); }
__device__ __forceinline__ unsigned f2bf(float f) {          // round-to-nearest-even
    unsigned u = __float_as_uint(f);
    return (u + 0x7fffu + ((u >> 16) & 1u)) >> 16;
}

// ------------------------------------------------- fused one-time prep
// grid 3125 x 256: castx (8 elems/thread), zero cnt/bcur, Wt = W^T bf16 x3.
__global__ __launch_bounds__(256) void prep_all(const float* __restrict__ x,
                                                unsigned short* __restrict__ xb,
                                                const float* __restrict__ W1,
                                                const float* __restrict__ W2,
                                                const float* __restrict__ W3,
                                                unsigned short* __restrict__ wt1,
                                                unsigned short* __restrict__ wt2,
                                                unsigned short* __restrict__ wt3,
                                                int* __restrict__ cnt,
                                                int* __restrict__ bcur) {
    int gid = blockIdx.x * 256 + threadIdx.x;
    int i = gid * 8;
    if (i + 7 < GCN_N * GCN_D) {
        float4 f0 = *(const float4*)&x[i];
        float4 f1 = *(const float4*)&x[i + 4];
        uint4 o;
        o.x = f2bf(f0.x) | (f2bf(f0.y) << 16);
        o.y = f2bf(f0.z) | (f2bf(f0.w) << 16);
        o.z = f2bf(f1.x) | (f2bf(f1.y) << 16);
        o.w = f2bf(f1.z) | (f2bf(f1.w) << 16);
        *(uint4*)&xb[i] = o;
    }
    if (gid < GCN_N) cnt[gid] = 0;
    if (gid < NBK) bcur[gid] = 0;
    if (gid < GCN_D * GCN_D) {
        int nn = gid >> 7, k = gid & 127;
        wt1[gid] = (unsigned short)f2bf(W1[k * 128 + nn]);
        wt2[gid] = (unsigned short)f2bf(W2[k * 128 + nn]);
        wt3[gid] = (unsigned short)f2bf(W3[k * 128 + nn]);
    }
}

// ------------------------------------------------- fill phase A: partition
// 2048 edges/block -> LDS stage grouped by bucket -> dense coalesced writes.
// No histogram here (that was r14's latency bomb).
__global__ __launch_bounds__(256) void fillA(const int* __restrict__ src,
                                             const int* __restrict__ dst,
                                             int* __restrict__ bcur,
                                             int2* __restrict__ pairs, int nE) {
    __shared__ int lcnt[NBK], lpre[NBK], lbase[NBK], lpos[NBK];
    __shared__ int2 stage[FA_BATCH];   // 16KB
    int tid = threadIdx.x;
    int base = blockIdx.x * FA_BATCH;
    if (tid < NBK) lcnt[tid] = 0;
    __syncthreads();
    int s[8], d[8], b[8];
    bool v[8];
    #pragma unroll
    for (int q = 0; q < 8; ++q) {
        int e = base + q * 256 + tid;     // coalesced per q
        v[q] = e < nE;
        s[q] = v[q] ? src[e] : 0;
        d[q] = v[q] ? dst[e] : 0;
        b[q] = d[q] >> 12;
        if (v[q]) atomicAdd(&lcnt[b[q]], 1);
    }
    __syncthreads();
    if (tid < NBK) {
        int pre = 0;
        for (int k = 0; k < tid; ++k) pre += lcnt[k];
        lpre[tid] = pre;
        lpos[tid] = pre;
        lbase[tid] = lcnt[tid] ? atomicAdd(&bcur[tid], lcnt[tid]) : 0;
    }
    __syncthreads();
    #pragma unroll
    for (int q = 0; q < 8; ++q)
        if (v[q]) {
            int off = atomicAdd(&lpos[b[q]], 1);
            stage[off] = make_int2(s[q], d[q]);
        }
    __syncthreads();
    int tot = lpre[NBK - 1] + lcnt[NBK - 1];
    for (int i = tid; i < tot; i += 256) {        // bucket-contiguous -> coalesced
        int2 p = stage[i];
        int bb = p.y >> 12;
        pairs[(size_t)bb * SEGCAP + lbase[bb] + (i - lpre[bb])] = p;
    }
}

// ------------------------------------------------- histogram, bucket-local
// grid 24x16: bucket = blockIdx&15 -> XCD b%8; cnt window 16KB L2-local.
__global__ __launch_bounds__(256) void histB(const int2* __restrict__ pairs,
                                             const int* __restrict__ bcur,
                                             int* __restrict__ cnt) {
    int b = blockIdx.x & (NBK - 1);
    int j = blockIdx.x >> 4;              // 0..23
    int cr = bcur[b];
    const int2* seg = pairs + (size_t)b * SEGCAP;
    for (int i = j * 256 + threadIdx.x; i < cr; i += 24 * 256)
        atomicAdd(&cnt[seg[i].y], 1);
}

// ------------------------------------------------- fill phase B: L2-local scatter
// Same grid/pinning as histB; row_ptr/cur/esrc windows L2-resident per bucket.
__global__ __launch_bounds__(256) void fillB(const int2* __restrict__ pairs,
                                             const int* __restrict__ bcur,
                                             const int* __restrict__ row_ptr,
                                             int* __restrict__ cur,
                                             int* __restrict__ esrc) {
    int b = blockIdx.x & (NBK - 1);
    int j = blockIdx.x >> 4;
    int cr = bcur[b];
    const int2* seg = pairs + (size_t)b * SEGCAP;
    for (int i = j * 256 + threadIdx.x; i < cr; i += 24 * 256) {
        int2 p = seg[i];
        int pos = row_ptr[p.y] + atomicAdd(&cur[p.y], 1);
        esrc[pos] = p.x;
    }
}

// ------------------------------------------------- multi-block prefix sum
__global__ __launch_bounds__(256) void block_reduce(const int* __restrict__ cnt,
                                                    int* __restrict__ bsum, int n) {
    int tid = threadIdx.x, lane = tid & 63, wid = tid >> 6;
    int i0 = blockIdx.x * 1024 + tid * 4;
    int s = 0;
    #pragma unroll
    for (int q = 0; q < 4; ++q)
        if (i0 + q < n) s += cnt[i0 + q];
    #pragma unroll
    for (int off = 32; off >= 1; off >>= 1) s += __shfl_xor(s, off);
    __shared__ int ws[4];
    if (lane == 0) ws[wid] = s;
    __syncthreads();
    if (tid == 0) bsum[blockIdx.x] = ws[0] + ws[1] + ws[2] + ws[3];
}

__global__ void scan_bsums(const int* __restrict__ bsum, int* __restrict__ boff,
                           int nb, int* __restrict__ row_last) {
    int lane = threadIdx.x;  // 64 threads
    int v = (lane < nb) ? bsum[lane] : 0;
    int sc = v;
    #pragma unroll
    for (int off = 1; off < 64; off <<= 1) {
        int t = __shfl_up(sc, off);
        if (lane >= off) sc += t;
    }
    if (lane < nb) boff[lane] = sc - v;
    if (lane == 63) *row_last = sc;  // row_ptr[N] = E
}

// row_ptr (exclusive scan), dinv = rsqrt(deg+1), zero cnt for fill cursor.
__global__ __launch_bounds__(256) void scan_apply(const int* __restrict__ cnt_in,
                                                  const int* __restrict__ boff,
                                                  int* __restrict__ row_ptr,
                                                  float* __restrict__ dinv,
                                                  int* __restrict__ cnt_zero, int n) {
    __shared__ int wsum[4];
    int tid = threadIdx.x, lane = tid & 63, wid = tid >> 6;
    int i0 = blockIdx.x * 1024 + tid * 4;
    int a0 = 0, a1 = 0, a2 = 0, a3 = 0;
    if (i0 + 0 < n) a0 = cnt_in[i0 + 0];
    if (i0 + 1 < n) a1 = cnt_in[i0 + 1];
    if (i0 + 2 < n) a2 = cnt_in[i0 + 2];
    if (i0 + 3 < n) a3 = cnt_in[i0 + 3];
    int tsum = a0 + a1 + a2 + a3;
    int sc = tsum;
    #pragma unroll
    for (int off = 1; off < 64; off <<= 1) {
        int t = __shfl_up(sc, off);
        if (lane >= off) sc += t;
    }
    if (lane == 63) wsum[wid] = sc;
    __syncthreads();
    int woff = 0;
    #pragma unroll
    for (int w = 0; w < 4; ++w)
        if (w < wid) woff += wsum[w];
    int excl = boff[blockIdx.x] + woff + (sc - tsum);
    if (i0 + 0 < n) { row_ptr[i0 + 0] = excl;                dinv[i0 + 0] = rsqrtf((float)a0 + 1.f); cnt_zero[i0 + 0] = 0; }
    if (i0 + 1 < n) { row_ptr[i0 + 1] = excl + a0;           dinv[i0 + 1] = rsqrtf((float)a1 + 1.f); cnt_zero[i0 + 1] = 0; }
    if (i0 + 2 < n) { row_ptr[i0 + 2] = excl + a0 + a1;      dinv[i0 + 2] = rsqrtf((float)a2 + 1.f); cnt_zero[i0 + 2] = 0; }
    if (i0 + 3 < n) { row_ptr[i0 + 3] = excl + a0 + a1 + a2; dinv[i0 + 3] = rsqrtf((float)a3 + 1.f); cnt_zero[i0 + 3] = 0; }
}

// ------------------------------------------------- fused BN folds (2 layers)
__global__ void prep_bn(const float* __restrict__ b1, const float* __restrict__ g1,
                        const float* __restrict__ be1, const float* __restrict__ m1,
                        const float* __restrict__ v1, float* __restrict__ scale1,
                        float* __restrict__ shift1,
                        const float* __restrict__ b2, const float* __restrict__ g2,
                        const float* __restrict__ be2, const float* __restrict__ m2,
                        const float* __restrict__ v2, float* __restrict__ scale2,
                        float* __restrict__ shift2) {
    int c = threadIdx.x;
    if (blockIdx.x == 0) {
        float s = g1[c] * rsqrtf(v1[c] + 1e-5f);
        scale1[c] = s;
        shift1[c] = (b1[c] - m1[c]) * s + be1[c];
    } else {
        float s = g2[c] * rsqrtf(v2[c] + 1e-5f);
        scale2[c] = s;
        shift2[c] = (b2[c] - m2[c]) * s + be2[c];
    }
}

// ---------------------------------------------------------------- MFMA matmul
// hb[node][128] (bf16) = dinv[node] * (A[node,:] @ W);  A bf16, Wt = W^T bf16.
// (identical to round-11 verified version)
__global__ __launch_bounds__(256) void mm_mfma(const unsigned short* __restrict__ A,
                                               const unsigned short* __restrict__ Wt,
                                               const float* __restrict__ dinv,
                                               unsigned short* __restrict__ hb, int n) {
    __shared__ unsigned short Cs[64][136];   // pad to 272B stride
    int tid = threadIdx.x;
    int w = tid >> 6, l = tid & 63;
    int lg = l >> 4, li = l & 15;
    int row0 = blockIdx.x * 64;

    int arow = row0 + w * 16 + li;
    int arow_c = min(arow, n - 1);
    const unsigned short* ap = A + (size_t)arow_c * GCN_D + lg * 8;
    bf16x8 a[4];
    #pragma unroll
    for (int k0 = 0; k0 < 4; ++k0) a[k0] = *(const bf16x8*)(ap + k0 * 32);

    f32x4 acc[8];
    #pragma unroll
    for (int t = 0; t < 8; ++t) acc[t] = (f32x4){0.f, 0.f, 0.f, 0.f};

    #pragma unroll
    for (int t = 0; t < 8; ++t) {
        const unsigned short* bp = Wt + (size_t)(t * 16 + li) * GCN_D + lg * 8;
        #pragma unroll
        for (int k0 = 0; k0 < 4; ++k0) {
            bf16x8 b = *(const bf16x8*)(bp + k0 * 32);
            acc[t] = __builtin_amdgcn_mfma_f32_16x16x32_bf16(a[k0], b, acc[t], 0, 0, 0);
        }
    }

    // epilogue: scale by dinv, pack bf16, stage in LDS
    int crow = w * 16 + lg * 4;
    float dv[4];
    #pragma unroll
    for (int r = 0; r < 4; ++r) dv[r] = dinv[min(row0 + crow + r, n - 1)];
    #pragma unroll
    for (int t = 0; t < 8; ++t)
        #pragma unroll
        for (int r = 0; r < 4; ++r)
            Cs[crow + r][t * 16 + li] = (unsigned short)f2bf(acc[t][r] * dv[r]);
    __syncthreads();

    // coalesced store: thread -> row tid>>2, 32-col chunk tid&3
    int orow = tid >> 2;
    int gr = row0 + orow;
    if (gr < n) {
        const unsigned short* sp = &Cs[orow][(tid & 3) * 32];
        uint4* dp = (uint4*)&hb[(size_t)gr * GCN_D + (tid & 3) * 32];
        dp[0] = *(const uint4*)(sp + 0);
        dp[1] = *(const uint4*)(sp + 8);
        dp[2] = *(const uint4*)(sp + 16);
        dp[3] = *(const uint4*)(sp + 24);
    }
}

// ------------------------------------------------- fused aggregate + epilogue
// (identical to round-11 verified version)
template <int FINAL>
__global__ __launch_bounds__(256) void agg_kernel(const unsigned short* __restrict__ hb,
                                                  const int* __restrict__ row_ptr,
                                                  const int* __restrict__ esrc,
                                                  const float* __restrict__ dinv,
                                                  const float* __restrict__ scale,
                                                  const float* __restrict__ shift,
                                                  const float* __restrict__ xres,
                                                  unsigned short* __restrict__ outb,
                                                  float* __restrict__ outf, int n) {
    int wid = threadIdx.x >> 6, lane = threadIdx.x & 63;
    int node = blockIdx.x * 4 + wid;
    if (node >= n) return;
    int cc = lane * 2;  // channel pair
    unsigned us = *(const unsigned*)&hb[(size_t)node * GCN_D + cc];
    float aLo = bflo(us), aHi = bfhi(us);   // self term h'[dst]
    float bLo = 0.f, bHi = 0.f;
    int j = row_ptr[node], end = row_ptr[node + 1];
    for (; j + 8 <= end; j += 8) {
        int s0 = esrc[j + 0], s1 = esrc[j + 1], s2 = esrc[j + 2], s3 = esrc[j + 3];
        int s4 = esrc[j + 4], s5 = esrc[j + 5], s6 = esrc[j + 6], s7 = esrc[j + 7];
        unsigned u0 = *(const unsigned*)&hb[(size_t)s0 * GCN_D + cc];
        unsigned u1 = *(const unsigned*)&hb[(size_t)s1 * GCN_D + cc];
        unsigned u2 = *(const unsigned*)&hb[(size_t)s2 * GCN_D + cc];
        unsigned u3 = *(const unsigned*)&hb[(size_t)s3 * GCN_D + cc];
        unsigned u4 = *(const unsigned*)&hb[(size_t)s4 * GCN_D + cc];
        unsigned u5 = *(const unsigned*)&hb[(size_t)s5 * GCN_D + cc];
        unsigned u6 = *(const unsigned*)&hb[(size_t)s6 * GCN_D + cc];
        unsigned u7 = *(const unsigned*)&hb[(size_t)s7 * GCN_D + cc];
        aLo += bflo(u0) + bflo(u1);  aHi += bfhi(u0) + bfhi(u1);
        bLo += bflo(u2) + bflo(u3);  bHi += bfhi(u2) + bfhi(u3);
        aLo += bflo(u4) + bflo(u5);  aHi += bfhi(u4) + bfhi(u5);
        bLo += bflo(u6) + bflo(u7);  bHi += bfhi(u6) + bfhi(u7);
    }
    for (; j < end; ++j) {
        int s = esrc[j];
        unsigned u = *(const unsigned*)&hb[(size_t)s * GCN_D + cc];
        aLo += bflo(u);  aHi += bfhi(u);
    }
    float dvn = dinv[node];
    float vx = (aLo + bLo) * dvn;
    float vy = (aHi + bHi) * dvn;
    if (FINAL) {
        float2 b = *(const float2*)&scale[cc];   // b3 passed via 'scale'
        float2 xr = *(const float2*)&xres[(size_t)node * GCN_D + cc];
        float2 o;
        o.x = vx + b.x + xr.x;
        o.y = vy + b.y + xr.y;
        *(float2*)&outf[(size_t)node * GCN_D + cc] = o;
    } else {
        float2 sc = *(const float2*)&scale[cc];
        float2 sh = *(const float2*)&shift[cc];
        float ox = fmaxf(vx * sc.x + sh.x, 0.f);
        float oy = fmaxf(vy * sc.y + sh.y, 0.f);
        *(unsigned*)&outb[(size_t)node * GCN_D + cc] = f2bf(ox) | (f2bf(oy) << 16);
    }
}

// ---------------------------------------------------------------- launch
extern "C" void kernel_launch(void* const* d_in, const int* in_sizes, int n_in,
                              void* d_out, int out_size, void* d_ws, size_t ws_size,
                              hipStream_t stream) {
    (void)in_sizes; (void)n_in; (void)out_size; (void)ws_size;
    const int N = GCN_N, E = GCN_E, D = GCN_D;

    const float* x   = (const float*)d_in[0];
    const float* W1  = (const float*)d_in[1];
    const float* b1  = (const float*)d_in[2];
    const float* g1  = (const float*)d_in[3];
    const float* be1 = (const float*)d_in[4];
    const float* m1  = (const float*)d_in[5];
    const float* v1  = (const float*)d_in[6];
    const float* W2  = (const float*)d_in[7];
    const float* b2  = (const float*)d_in[8];
    const float* g2  = (const float*)d_in[9];
    const float* be2 = (const float*)d_in[10];
    const float* m2  = (const float*)d_in[11];
    const float* v2  = (const float*)d_in[12];
    const float* W3  = (const float*)d_in[13];
    const float* b3  = (const float*)d_in[14];
    const int* src   = (const int*)d_in[15];
    const int* dst   = (const int*)d_in[16];
    float* out = (float*)d_out;

    // workspace layout (bf16 buffers first, then 4/8B-typed)
    unsigned short* hb   = (unsigned short*)d_ws;        // N*D bf16
    unsigned short* actb = hb + (size_t)N * D;           // N*D bf16
    unsigned short* xb   = actb + (size_t)N * D;         // N*D bf16
    unsigned short* wt1  = xb + (size_t)N * D;           // 16384
    unsigned short* wt2  = wt1 + D * D;
    unsigned short* wt3  = wt2 + D * D;
    float* dinv   = (float*)(wt3 + D * D);               // N (even short count)
    int* cnt      = (int*)(dinv + N);                    // N
    int* row_ptr  = cnt + N;                             // N+1
    int* esrc     = row_ptr + (N + 2);                   // E
    float* scale1 = (float*)(esrc + E);                  // 128
    float* shift1 = scale1 + D;
    float* scale2 = shift1 + D;
    float* shift2 = scale2 + D;
    int* bsum     = (int*)(shift2 + D);                  // 64
    int* boff     = bsum + 64;                           // 64
    int* bcur     = boff + 64;                           // NBK = 16
    int2* pairs   = (int2*)(bcur + 64);                  // NBK*SEGCAP (9.4MB)

    const int NB = (N + 1023) / 1024;  // 49 scan blocks

    // ---- one-time prep + CSR build
    prep_all<<<(N * D) / (256 * 8), 256, 0, stream>>>(x, xb, W1, W2, W3,
                                                      wt1, wt2, wt3, cnt, bcur);
    fillA<<<(E + FA_BATCH - 1) / FA_BATCH, 256, 0, stream>>>(src, dst, bcur, pairs, E);
    histB<<<24 * NBK, 256, 0, stream>>>(pairs, bcur, cnt);
    block_reduce<<<NB, 256, 0, stream>>>(cnt, bsum, N);
    scan_bsums<<<1, 64, 0, stream>>>(bsum, boff, NB, &row_ptr[N]);
    scan_apply<<<NB, 256, 0, stream>>>(cnt, boff, row_ptr, dinv, cnt, N);
    fillB<<<24 * NBK, 256, 0, stream>>>(pairs, bcur, row_ptr, cnt, esrc);
    prep_bn<<<2, D, 0, stream>>>(b1, g1, be1, m1, v1, scale1, shift1,
                                 b2, g2, be2, m2, v2, scale2, shift2);

    int mm_grid = (N + 63) / 64;
    int agg_grid = (N + 3) / 4;

    // ---- layer 1
    mm_mfma<<<mm_grid, 256, 0, stream>>>(xb, wt1, dinv, hb, N);
    agg_kernel<0><<<agg_grid, 256, 0, stream>>>(hb, row_ptr, esrc, dinv,
                                                scale1, shift1, nullptr, actb, nullptr, N);
    // ---- layer 2
    mm_mfma<<<mm_grid, 256, 0, stream>>>(actb, wt2, dinv, hb, N);
    agg_kernel<0><<<agg_grid, 256, 0, stream>>>(hb, row_ptr, esrc, dinv,
                                                scale2, shift2, nullptr, actb, nullptr, N);
    // ---- layer 3 (+bias +residual, writes fp32 d_out)
    mm_mfma<<<mm_grid, 256, 0, stream>>>(actb, wt3, dinv, hb, N);
    agg_kernel<1><<<agg_grid, 256, 0, stream>>>(hb, row_ptr, esrc, dinv,
                                                b3, nullptr, x, nullptr, out, N);
}